// Round 7
// baseline (235.593 us; speedup 1.0000x reference)
//
#include <hip/hip_runtime.h>
#include <hip/hip_bf16.h>

// NT-Xent (SimCLR) fused loss, MI355X gfx950. Round 15: one tile/block +
// fused finalize. r14 (no LDS, no barriers) won -5us but simclr still ~4x
// its busy-work. Remaining structural costs: (1) the 32 five-tile blocks
// set the critical path (~20% tail) at exactly 2 blocks/CU; (2) 2 waves/
// SIMD is grid-limited; phases can't interleave (r10's "more waves" null
// was measured WITH barriers -- untested in the free-run regime); (3) 4
// dispatches/iter of launch gaps. This round: grid 2080, ONE 128x128 tile
// per block (identical work, zero tail, 8.1 blocks/CU turnover at
// LB(256,3) = 12 waves/CU resident); finalize fused into simclr via
// last-block counter (agent-scope atomics); 3 dispatches total.
//
// ws layout: [S: N f32][pos: N f32][cnt: u32 + pad][znf: N*D fp8 frag-major]

#define N_TOT 8192
#define BATCH 4096
#define DIM   256                    // fp8 bytes per row
#define NBLK  2080                   // 64 bands * 32 offsets + 32 partners
#define LOG2E_T 14.4269504089f       // 10 * log2(e)  (temperature folded)

typedef int   v8i32 __attribute__((ext_vector_type(8)));
typedef float f32x4 __attribute__((ext_vector_type(4)));

// znf layout: for 16-row group G (rows G*16+c, c=0..15), k-half h (0/1),
// quad q (0..3): 512-byte block at ((G*2+h)*4+q)*512. Lane c's 32 bytes
// (row G*16+c, row-bytes [16*(8h+2q), +32)) live contiguously at c*32.

// One wave per row: 64 lanes x float4 -> 4 fp8 bytes/lane, scattered into
// fragment-major znf. Also zeros S, the block counter, and out.
__global__ __launch_bounds__(256) void normalize_kernel(
    const float* __restrict__ z, unsigned char* __restrict__ znf,
    float* __restrict__ S, unsigned int* __restrict__ cnt,
    float* __restrict__ out) {
  const int wave = threadIdx.x >> 6;
  const int lane = threadIdx.x & 63;
  const int row  = blockIdx.x * 4 + wave;
  float4 v = ((const float4*)(z + (size_t)row * DIM))[lane];
  float ss = v.x * v.x + v.y * v.y + v.z * v.z + v.w * v.w;
#pragma unroll
  for (int m = 1; m <= 32; m <<= 1) ss += __shfl_xor(ss, m);
  float inv = 1.0f / sqrtf(ss);
  int p01 = __builtin_amdgcn_cvt_pk_fp8_f32(v.x * inv, v.y * inv, 0, false);
  int p23 = __builtin_amdgcn_cvt_pk_fp8_f32(v.z * inv, v.w * inv, 0, false);
  unsigned int packed =
      ((unsigned int)p01 & 0xffffu) | ((unsigned int)p23 << 16);
  // This thread holds row-words w = lane: h = w>>5, q = (w>>3)&3,
  // 16B-half lb = (w>>2)&1, word-in-16B = w&3.
  const int G = row >> 4, c = row & 15;
  const int h = lane >> 5, q = (lane >> 3) & 3, lb = (lane >> 2) & 1;
  *(unsigned int*)(znf + (((size_t)(G * 2 + h) * 4 + q) << 9) + c * 32 +
                   lb * 16 + (lane & 3) * 4) = packed;
  if (threadIdx.x < 4) S[blockIdx.x * 4 + threadIdx.x] = 0.0f;
  if (blockIdx.x == 0 && threadIdx.x == 0) { out[0] = 0.0f; *cnt = 0u; }
}

// Load one (row-group, k-half) fragment (32 B/lane) straight from L2.
__device__ __forceinline__ v8i32 load_frag_g(
    const unsigned char* __restrict__ znf, int G, int h, int quad, int c) {
  const int4* p =
      (const int4*)(znf + (((size_t)(G * 2 + h) * 4 + quad) << 9) + c * 32);
  int4 lo = p[0];
  int4 hi = p[1];
  return (v8i32){lo.x, lo.y, lo.z, lo.w, hi.x, hi.y, hi.z, hi.w};
}

// Tile epilogue: register-only. MODE 0 = plain, 1 = diagonal (mask
// self-sim; caller skips col flush -- symmetric, rows cover), 2 = partner
// (jj==32: emit pos logits, agent-scope stores).
template <int MODE>
__device__ __forceinline__ void epilogue_tile(
    const f32x4 (&acc)[4][4], float (&rs)[16], float (&cs)[4],
    float* __restrict__ pos, int rb, int cbt, int wm, int wn, int c,
    int quad) {
#pragma unroll
  for (int fm = 0; fm < 4; ++fm) {
#pragma unroll
    for (int r = 0; r < 4; ++r) {
      const int grow = rb * 128 + wm * 64 + fm * 16 + quad * 4 + r;
#pragma unroll
      for (int fn = 0; fn < 4; ++fn) {
        const int gcol = cbt * 128 + wn * 64 + fn * 16 + c;
        // exp(acc*10) == exp2(acc * 10*log2(e)); raw v_exp_f32, no libcall
        float e = __builtin_amdgcn_exp2f(acc[fm][fn][r] * LOG2E_T);
        if (MODE == 1 && gcol == grow) e = 0.f;   // exclude self-similarity
        if (MODE == 2 && ((gcol ^ grow) == BATCH)) {
          const float logit = acc[fm][fn][r] * 10.0f;
          __hip_atomic_store(&pos[grow], logit, __ATOMIC_RELAXED,
                             __HIP_MEMORY_SCOPE_AGENT);
          __hip_atomic_store(&pos[gcol], logit, __ATOMIC_RELAXED,
                             __HIP_MEMORY_SCOPE_AGENT);
        }
        rs[fm * 4 + r] += e;
        cs[fn] += e;
      }
    }
  }
}

// One 128x128 tile per block. bid<2048: rb=bid>>5, jj=bid&31 (jj==0 diag);
// bid>=2048: rb=bid-2048, jj=32 (partner tile, rb<32).
__global__ __launch_bounds__(256, 3) void simclr_tile_kernel(
    const unsigned char* __restrict__ znf, float* __restrict__ S,
    float* __restrict__ pos, unsigned int* __restrict__ cnt,
    float* __restrict__ out) {
  const int bid = blockIdx.x;
  const int tid = threadIdx.x;
  const int wave = tid >> 6, lane = tid & 63;
  const int wm = wave >> 1, wn = wave & 1;     // wave quadrant (2x2)
  const int c = lane & 15, quad = lane >> 4;   // MFMA lane coords

  int rb, jj;
  if (bid < 2048) { rb = bid >> 5; jj = bid & 31; }
  else            { rb = bid - 2048; jj = 32; }
  const int cbt = (rb + jj) & 63;

  // A- and B-fragments straight from L2 (znf is 2MB, L2-resident).
  v8i32 af[4][2], bf[4][2];
#pragma unroll
  for (int f = 0; f < 4; ++f)
#pragma unroll
    for (int h = 0; h < 2; ++h) {
      af[f][h] = load_frag_g(znf, rb * 8 + wm * 4 + f, h, quad, c);
      bf[f][h] = load_frag_g(znf, cbt * 8 + wn * 4 + f, h, quad, c);
    }

  f32x4 acc[4][4];
#pragma unroll
  for (int i = 0; i < 4; ++i)
#pragma unroll
    for (int k = 0; k < 4; ++k) acc[i][k] = (f32x4){0.f, 0.f, 0.f, 0.f};

#pragma unroll
  for (int h = 0; h < 2; ++h)
#pragma unroll
    for (int fm = 0; fm < 4; ++fm)
#pragma unroll
      for (int fn = 0; fn < 4; ++fn)
        acc[fm][fn] = __builtin_amdgcn_mfma_scale_f32_16x16x128_f8f6f4(
            af[fm][h], bf[fn][h], acc[fm][fn],
            0, 0,                 // cbsz = fp8(A), blgp = fp8(B)
            0, 0x7f,              // opsel_a, scale_a = E8M0 1.0
            0, 0x7f);             // opsel_b, scale_b = E8M0 1.0

  // Register epilogue (block-uniform mode branch).
  float rs[16];
#pragma unroll
  for (int i = 0; i < 16; ++i) rs[i] = 0.f;
  float cs[4] = {0.f, 0.f, 0.f, 0.f};
  if (jj == 0)
    epilogue_tile<1>(acc, rs, cs, pos, rb, cbt, wm, wn, c, quad);
  else if (jj == 32)
    epilogue_tile<2>(acc, rs, cs, pos, rb, cbt, wm, wn, c, quad);
  else
    epilogue_tile<0>(acc, rs, cs, pos, rb, cbt, wm, wn, c, quad);

  // Row sums: shuffle-reduce + one atomic per row.
#pragma unroll
  for (int fm = 0; fm < 4; ++fm) {
#pragma unroll
    for (int r = 0; r < 4; ++r) {
      float s = rs[fm * 4 + r];
      s += __shfl_xor(s, 1);
      s += __shfl_xor(s, 2);
      s += __shfl_xor(s, 4);
      s += __shfl_xor(s, 8);
      if (c == 0) {
        const int grow = rb * 128 + wm * 64 + fm * 16 + quad * 4 + r;
        atomicAdd(&S[grow], s);
      }
    }
  }

  // Column sums (transpose contribution); diag tile skipped (symmetric).
  if (jj != 0) {
#pragma unroll
    for (int fn = 0; fn < 4; ++fn) {
      float v = cs[fn];
      v += __shfl_xor(v, 16);
      v += __shfl_xor(v, 32);
      if (quad == 0)
        atomicAdd(&S[cbt * 128 + wn * 64 + fn * 16 + c], v);
    }
  }

  // ---- Fused finalize: last block to finish reduces loss. ----
  __threadfence();                         // publish our S/pos updates
  __shared__ unsigned int lastflag;
  if (tid == 0) {
    unsigned int prev = __hip_atomic_fetch_add(
        cnt, 1u, __ATOMIC_ACQ_REL, __HIP_MEMORY_SCOPE_AGENT);
    lastflag = (prev == NBLK - 1) ? 1u : 0u;
  }
  __syncthreads();
  if (lastflag) {
    __threadfence();
    float a = 0.f;
    for (int i = tid; i < N_TOT; i += 256) {
      float sv = __hip_atomic_load(&S[i], __ATOMIC_RELAXED,
                                   __HIP_MEMORY_SCOPE_AGENT);
      float pv = __hip_atomic_load(&pos[i], __ATOMIC_RELAXED,
                                   __HIP_MEMORY_SCOPE_AGENT);
      a += __logf(sv) - pv;
    }
#pragma unroll
    for (int m = 1; m <= 32; m <<= 1) a += __shfl_xor(a, m);
    __shared__ float red[4];
    if ((tid & 63) == 0) red[tid >> 6] = a;
    __syncthreads();
    if (tid == 0)
      out[0] = (red[0] + red[1] + red[2] + red[3]) * (1.0f / (float)N_TOT);
  }
}

extern "C" void kernel_launch(void* const* d_in, const int* in_sizes, int n_in,
                              void* d_out, int out_size, void* d_ws,
                              size_t ws_size, hipStream_t stream) {
  const float* z = (const float*)d_in[0];
  float* out = (float*)d_out;
  char* ws = (char*)d_ws;
  float* S = (float*)ws;                                   // N floats
  float* pos = (float*)(ws + N_TOT * sizeof(float));       // N floats
  unsigned int* cnt =
      (unsigned int*)(ws + 2 * N_TOT * sizeof(float));     // u32 + pad
  unsigned char* znf =
      (unsigned char*)(ws + 2 * N_TOT * sizeof(float) + 64);  // N*D fp8

  normalize_kernel<<<N_TOT / 4, 256, 0, stream>>>(z, znf, S, cnt, out);
  simclr_tile_kernel<<<NBLK, 256, 0, stream>>>(znf, S, pos, cnt, out);
}

// Round 8
// 94.108 us; speedup vs baseline: 2.5034x; 2.5034x over previous
//
#include <hip/hip_runtime.h>
#include <hip/hip_bf16.h>

// NT-Xent (SimCLR) fused loss, MI355X gfx950. Round 16: r15 minus fences.
// r15 post-mortem: 185us regression with occupancy UP (27%) and MfmaUtil
// DOWN (1.8%) -- resident-but-stalled. Cause: per-block __threadfence
// (agent seq-cst -> buffer_wbl2/buffer_inv = full per-XCD L2 writeback+
// invalidate) x 2080 blocks = continuous L2 thrash; fragment loads became
// L3-latency misses (invisible in FETCH_SIZE, which is HBM-only). This
// round keeps the uniform one-tile-per-block grid (2080 blocks -- the
// clean tail fix) and fragment-direct loads, but drops ALL fence/counter
// machinery: finalize is its own dispatch again (kernel boundary = sync).
//
// ws layout: [S: N f32][pos: N f32][znf: N*D fp8 frag-major]

#define N_TOT 8192
#define BATCH 4096
#define DIM   256                    // fp8 bytes per row
#define NBLK  2080                   // 64*32 tiles + 32 partner tiles
#define LOG2E_T 14.4269504089f       // 10 * log2(e)  (temperature folded)

typedef int   v8i32 __attribute__((ext_vector_type(8)));
typedef float f32x4 __attribute__((ext_vector_type(4)));

// znf layout: for 16-row group G (rows G*16+c, c=0..15), k-half h (0/1),
// quad q (0..3): 512-byte block at ((G*2+h)*4+q)*512. Lane c's 32 bytes
// (row G*16+c, row-bytes [16*(8h+2q), +32)) live contiguously at c*32.

// One wave per row: 64 lanes x float4 -> 4 fp8 bytes/lane, scattered into
// fragment-major znf. Also zeros S.
__global__ __launch_bounds__(256) void normalize_kernel(
    const float* __restrict__ z, unsigned char* __restrict__ znf,
    float* __restrict__ S) {
  const int wave = threadIdx.x >> 6;
  const int lane = threadIdx.x & 63;
  const int row  = blockIdx.x * 4 + wave;
  float4 v = ((const float4*)(z + (size_t)row * DIM))[lane];
  float ss = v.x * v.x + v.y * v.y + v.z * v.z + v.w * v.w;
#pragma unroll
  for (int m = 1; m <= 32; m <<= 1) ss += __shfl_xor(ss, m);
  float inv = 1.0f / sqrtf(ss);
  int p01 = __builtin_amdgcn_cvt_pk_fp8_f32(v.x * inv, v.y * inv, 0, false);
  int p23 = __builtin_amdgcn_cvt_pk_fp8_f32(v.z * inv, v.w * inv, 0, false);
  unsigned int packed =
      ((unsigned int)p01 & 0xffffu) | ((unsigned int)p23 << 16);
  // This thread holds row-words w = lane: h = w>>5, q = (w>>3)&3,
  // 16B-half lb = (w>>2)&1, word-in-16B = w&3.
  const int G = row >> 4, c = row & 15;
  const int h = lane >> 5, q = (lane >> 3) & 3, lb = (lane >> 2) & 1;
  *(unsigned int*)(znf + (((size_t)(G * 2 + h) * 4 + q) << 9) + c * 32 +
                   lb * 16 + (lane & 3) * 4) = packed;
  if (threadIdx.x < 4) S[blockIdx.x * 4 + threadIdx.x] = 0.0f;
}

// Load one (row-group, k-half) fragment (32 B/lane) straight from L2.
__device__ __forceinline__ v8i32 load_frag_g(
    const unsigned char* __restrict__ znf, int G, int h, int quad, int c) {
  const int4* p =
      (const int4*)(znf + (((size_t)(G * 2 + h) * 4 + quad) << 9) + c * 32);
  int4 lo = p[0];
  int4 hi = p[1];
  return (v8i32){lo.x, lo.y, lo.z, lo.w, hi.x, hi.y, hi.z, hi.w};
}

// Tile epilogue: register-only. MODE 0 = plain, 1 = diagonal (mask
// self-sim; caller skips col flush -- symmetric, rows cover), 2 = partner
// (jj==32: emit pos logits, plain stores -- next kernel boundary syncs).
template <int MODE>
__device__ __forceinline__ void epilogue_tile(
    const f32x4 (&acc)[4][4], float (&rs)[16], float (&cs)[4],
    float* __restrict__ pos, int rb, int cbt, int wm, int wn, int c,
    int quad) {
#pragma unroll
  for (int fm = 0; fm < 4; ++fm) {
#pragma unroll
    for (int r = 0; r < 4; ++r) {
      const int grow = rb * 128 + wm * 64 + fm * 16 + quad * 4 + r;
#pragma unroll
      for (int fn = 0; fn < 4; ++fn) {
        const int gcol = cbt * 128 + wn * 64 + fn * 16 + c;
        // exp(acc*10) == exp2(acc * 10*log2(e)); raw v_exp_f32, no libcall
        float e = __builtin_amdgcn_exp2f(acc[fm][fn][r] * LOG2E_T);
        if (MODE == 1 && gcol == grow) e = 0.f;   // exclude self-similarity
        if (MODE == 2 && ((gcol ^ grow) == BATCH)) {
          const float logit = acc[fm][fn][r] * 10.0f;
          pos[grow] = logit;                       // unique writer/elem
          pos[gcol] = logit;                       // sim symmetric
        }
        rs[fm * 4 + r] += e;
        cs[fn] += e;
      }
    }
  }
}

// One 128x128 tile per block. bid<2048: rb=bid>>5, jj=bid&31 (jj==0 diag);
// bid>=2048: rb=bid-2048, jj=32 (partner tile, rb<32).
__global__ __launch_bounds__(256, 3) void simclr_tile_kernel(
    const unsigned char* __restrict__ znf, float* __restrict__ S,
    float* __restrict__ pos) {
  const int bid = blockIdx.x;
  const int tid = threadIdx.x;
  const int wave = tid >> 6, lane = tid & 63;
  const int wm = wave >> 1, wn = wave & 1;     // wave quadrant (2x2)
  const int c = lane & 15, quad = lane >> 4;   // MFMA lane coords

  int rb, jj;
  if (bid < 2048) { rb = bid >> 5; jj = bid & 31; }
  else            { rb = bid - 2048; jj = 32; }
  const int cbt = (rb + jj) & 63;

  // A- and B-fragments straight from L2 (znf is 2MB, L2-resident).
  v8i32 af[4][2], bf[4][2];
#pragma unroll
  for (int f = 0; f < 4; ++f)
#pragma unroll
    for (int h = 0; h < 2; ++h) {
      af[f][h] = load_frag_g(znf, rb * 8 + wm * 4 + f, h, quad, c);
      bf[f][h] = load_frag_g(znf, cbt * 8 + wn * 4 + f, h, quad, c);
    }

  f32x4 acc[4][4];
#pragma unroll
  for (int i = 0; i < 4; ++i)
#pragma unroll
    for (int k = 0; k < 4; ++k) acc[i][k] = (f32x4){0.f, 0.f, 0.f, 0.f};

#pragma unroll
  for (int h = 0; h < 2; ++h)
#pragma unroll
    for (int fm = 0; fm < 4; ++fm)
#pragma unroll
      for (int fn = 0; fn < 4; ++fn)
        acc[fm][fn] = __builtin_amdgcn_mfma_scale_f32_16x16x128_f8f6f4(
            af[fm][h], bf[fn][h], acc[fm][fn],
            0, 0,                 // cbsz = fp8(A), blgp = fp8(B)
            0, 0x7f,              // opsel_a, scale_a = E8M0 1.0
            0, 0x7f);             // opsel_b, scale_b = E8M0 1.0

  // Register epilogue (block-uniform mode branch).
  float rs[16];
#pragma unroll
  for (int i = 0; i < 16; ++i) rs[i] = 0.f;
  float cs[4] = {0.f, 0.f, 0.f, 0.f};
  if (jj == 0)
    epilogue_tile<1>(acc, rs, cs, pos, rb, cbt, wm, wn, c, quad);
  else if (jj == 32)
    epilogue_tile<2>(acc, rs, cs, pos, rb, cbt, wm, wn, c, quad);
  else
    epilogue_tile<0>(acc, rs, cs, pos, rb, cbt, wm, wn, c, quad);

  // Row sums: shuffle-reduce + one atomic per row.
#pragma unroll
  for (int fm = 0; fm < 4; ++fm) {
#pragma unroll
    for (int r = 0; r < 4; ++r) {
      float s = rs[fm * 4 + r];
      s += __shfl_xor(s, 1);
      s += __shfl_xor(s, 2);
      s += __shfl_xor(s, 4);
      s += __shfl_xor(s, 8);
      if (c == 0) {
        const int grow = rb * 128 + wm * 64 + fm * 16 + quad * 4 + r;
        atomicAdd(&S[grow], s);
      }
    }
  }

  // Column sums (transpose contribution); diag tile skipped (symmetric).
  if (jj != 0) {
#pragma unroll
    for (int fn = 0; fn < 4; ++fn) {
      float v = cs[fn];
      v += __shfl_xor(v, 16);
      v += __shfl_xor(v, 32);
      if (quad == 0)
        atomicAdd(&S[cbt * 128 + wn * 64 + fn * 16 + c], v);
    }
  }
}

// loss = mean(log(S_i) - pos_i); single block (cheap, ~2us).
__global__ __launch_bounds__(1024) void finalize_kernel(
    const float* __restrict__ S, const float* __restrict__ pos,
    float* __restrict__ out) {
  const int tid = threadIdx.x;
  float a = 0.f;
  for (int i = tid; i < N_TOT; i += 1024) a += __logf(S[i]) - pos[i];
#pragma unroll
  for (int m = 1; m <= 32; m <<= 1) a += __shfl_xor(a, m);
  __shared__ float red[16];
  if ((tid & 63) == 0) red[tid >> 6] = a;
  __syncthreads();
  if (tid < 16) {
    float v = red[tid];
    v += __shfl_xor(v, 1);
    v += __shfl_xor(v, 2);
    v += __shfl_xor(v, 4);
    v += __shfl_xor(v, 8);
    if (tid == 0) out[0] = v * (1.0f / (float)N_TOT);
  }
}

extern "C" void kernel_launch(void* const* d_in, const int* in_sizes, int n_in,
                              void* d_out, int out_size, void* d_ws,
                              size_t ws_size, hipStream_t stream) {
  const float* z = (const float*)d_in[0];
  float* out = (float*)d_out;
  char* ws = (char*)d_ws;
  float* S = (float*)ws;                                   // N floats
  float* pos = (float*)(ws + N_TOT * sizeof(float));       // N floats
  unsigned char* znf =
      (unsigned char*)(ws + 2 * N_TOT * sizeof(float));    // N*D fp8

  normalize_kernel<<<N_TOT / 4, 256, 0, stream>>>(z, znf, S);
  simclr_tile_kernel<<<NBLK, 256, 0, stream>>>(znf, S, pos);
  finalize_kernel<<<1, 1024, 0, stream>>>(S, pos, out);
}